// Round 19
// baseline (148.337 us; speedup 1.0000x reference)
//
#include <hip/hip_runtime.h>
#include <hip/hip_bf16.h>

constexpr int B = 4;
constexpr int N = 1024;
constexpr int D = 1024;
constexpr int H = 16;
constexpr int DEPTH = 64;
constexpr int W = 32;
constexpr int LDQKV = 3072;   // fused q|k|v row stride (f16 elements)
constexpr int SROWS = 8704;   // attn rows [0,SROWS) hold pass1-LIVE scratch

typedef _Float16 f16x8 __attribute__((ext_vector_type(8)));
typedef float f32x4 __attribute__((ext_vector_type(4)));
typedef unsigned short us8 __attribute__((ext_vector_type(8)));
typedef unsigned short us4 __attribute__((ext_vector_type(4)));

__device__ __forceinline__ float h2f(unsigned short u) {
  return (float)__builtin_bit_cast(_Float16, u);
}

// ---------------------------------------------------------------------------
// async global->LDS, 16B per lane (wave-uniform LDS base, HW adds lane*16)
// ---------------------------------------------------------------------------
__device__ __forceinline__ void load_lds16(const void* g, void* l) {
  unsigned int lo = (unsigned int)(unsigned long long)l;
  __builtin_amdgcn_global_load_lds(
      (const __attribute__((address_space(1))) unsigned int*)g,
      (__attribute__((address_space(3))) unsigned int*)lo, 16, 0, 0);
}

// ---------------------------------------------------------------------------
// attn-row fill helper: base everywhere, p at graph positions, NT store.
// Barriers between mixed f32x4/float LDS accesses are REQUIRED (TBAA).
// ---------------------------------------------------------------------------
__device__ __forceinline__ void fill_row(float* rowf, const float* pbuf,
                                         const float* basebuf,
                                         const int* graph, float* attn,
                                         int row, int t) {
  const int n = row & (N - 1);
  const float base = basebuf[row];
  f32x4* rw = (f32x4*)rowf;
  rw[t] = (f32x4){base, base, base, base};
  __syncthreads();
  if (t < W) rowf[graph[n * W + t]] = pbuf[(size_t)row * W + t];
  __syncthreads();
  __builtin_nontemporal_store(rw[t], (f32x4*)(attn + (size_t)row * N) + t);
}

// ---------------------------------------------------------------------------
// Fused prep (cvt_half ELIMINATED — gemm_qkv stages hidden f32 directly):
//   [0, 1024)    txp_cvt: wq/wk/wv/wo -> transposed fp16 (hi only)
//   [1024, 1036) bias_concat
// ---------------------------------------------------------------------------
__global__ __launch_bounds__(256) void prep_all(
    const float* __restrict__ wq, const float* __restrict__ wk,
    const float* __restrict__ wv, const float* __restrict__ wo,
    const float* __restrict__ bq, const float* __restrict__ bk,
    const float* __restrict__ bv, unsigned short* __restrict__ BTh,
    unsigned short* __restrict__ WoTh, float* __restrict__ biasq) {
  __shared__ float sf[64][65];
  const int t = threadIdx.x;
  int blk = blockIdx.x;

  if (blk < 1024) {  // ---- txp_cvt sections (4 weights x 256 blocks) ----
    const int which = blk >> 8;       // 0=wq 1=wk 2=wv 3=wo
    const int sub = blk & 255;
    const float* w = which == 0 ? wq : which == 1 ? wk : which == 2 ? wv : wo;
    unsigned short* oh = which < 3 ? BTh : WoTh;
    const int rowOff = which < 3 ? which * 1024 : 0;

    const int tn = (sub & 15) * 64;   // src col block
    const int tk = (sub >> 4) * 64;   // src row block
#pragma unroll
    for (int i = 0; i < 4; i++) {
      int f = i * 256 + t;
      int r = f >> 4, c4 = (f & 15) * 4;
      float4 v = *(const float4*)(w + (size_t)(tk + r) * 1024 + tn + c4);
      sf[r][c4 + 0] = v.x; sf[r][c4 + 1] = v.y;
      sf[r][c4 + 2] = v.z; sf[r][c4 + 3] = v.w;
    }
    __syncthreads();
    const int n = t >> 2;             // out row (src col)
    const int kc = (t & 3) * 16;      // k chunk
    us8 hv[2];
#pragma unroll
    for (int half = 0; half < 2; half++) {
#pragma unroll
      for (int j = 0; j < 8; j++) {
        float x = sf[kc + half * 8 + j][n];
        hv[half][j] = __builtin_bit_cast(unsigned short, (_Float16)x);
      }
    }
    size_t dst = (size_t)(rowOff + tn + n) * 1024 + tk + kc;
    *(us8*)(oh + dst) = hv[0];
    *(us8*)(oh + dst + 8) = hv[1];
    return;
  }
  blk -= 1024;  // ---- bias_concat section (12 blocks) ----
  int i = blk * 256 + t;
  biasq[i] = i < 1024 ? bq[i] : (i < 2048 ? bk[i - 1024] : bv[i - 2048]);
}

// ---------------------------------------------------------------------------
// QKV GEMM (round-17 geometry, A-path now f32-direct): 128x256 tile,
// wave = 64x128 (acc 4x8), BK=32, 4 waves, 2-phase dbuf.
// A staged as fp32 straight from `hidden` (no cvt_half pass); convert to
// fp16 in-register after ds_read (same rne -> bit-identical).
// A swizzle: 16B granules, 8/row, src g^(r&7); fragment = two b128 reads at
// granules (2*fkg)^s and ^s^1 (same involution on stage + read, rule #21).
// B path unchanged (f16, verified). LDS 64 KB (A f32 32K + B f16 32K).
// T1 XCD swizzle (384 blocks %8==0); T5 setprio. V-column blocks emit
// column-sum partials; vred overlays sA after the final barrier.
// ---------------------------------------------------------------------------
__global__ __launch_bounds__(256, 2) void gemm_qkv(
    const float* __restrict__ hidden, const unsigned short* __restrict__ BTh,
    const float* __restrict__ bias, unsigned short* __restrict__ Cout,
    float* __restrict__ vpart, int K, int Nn) {
  __shared__ __align__(16) float sA[2 * 128 * 32];            // f32 A planes
  __shared__ __align__(16) unsigned short sB[2 * 256 * 32];   // f16 B planes

  const int tid = threadIdx.x;
  const int lane = tid & 63;
  const int wave = tid >> 6;
  const int wr = wave >> 1, wc = wave & 1;

  // T1 XCD-aware swizzle (nwg = 384, %8==0)
  const int gx = gridDim.x;
  const int nwg = gx * gridDim.y;
  int bid = blockIdx.y * gx + blockIdx.x;
  bid = (bid & 7) * (nwg >> 3) + (bid >> 3);
  const int bm = (bid / gx) * 128;
  const int bn = (bid % gx) * 256;

  // A staging (f32): plane [128][32] f32 = 16 KB = 16 chunks of 1 KB;
  // wave stages chunks {wave + 4c}. Per-lane: one 16B granule (4 f32).
  size_t aoff[4];
  int ldsA[4];                         // f32 element offsets
#pragma unroll
  for (int c = 0; c < 4; c++) {
    const int chunk = wave + 4 * c;
    const int e = chunk * 256 + lane * 4;   // linear f32 element
    const int r = e >> 5;                   // tile row (32 f32/row)
    const int g = (e >> 2) & 7;             // 16B granule in row (8/row)
    const int gs = g ^ (r & 7);             // swizzled source granule
    aoff[c] = (size_t)(bm + r) * K + gs * 4;
    ldsA[c] = chunk * 256;
  }
  // B staging (f16): plane [256][32] f16 = 16 KB = 16 chunks; wave stages 4.
  size_t boff[4];
  int ldsB[4];
#pragma unroll
  for (int c = 0; c < 4; c++) {
    const int chunk = wave + 4 * c;
    const int e = chunk * 512 + lane * 8;   // linear f16 element
    const int r = e >> 5;                   // tile row 0..255
    const int kpos = (e >> 3) & 3;          // 16B granule in row (4/row)
    const int ksrc = kpos ^ ((r >> 1) & 3); // swizzled source granule
    boff[c] = (size_t)(bn + r) * K + ksrc * 8;
    ldsB[c] = chunk * 512;
  }

  const int fr = lane & 15;
  const int fkg = lane >> 4;

  // A fragment reads: row ra, k = fkg*8..+7 -> granules (2fkg)^s, (2fkg)^s^1
  int ar0[4], ar1[4];
#pragma unroll
  for (int m = 0; m < 4; m++) {
    const int ra = wr * 64 + m * 16 + fr;
    const int s = ra & 7;
    const int g0 = (2 * fkg) ^ s;
    ar0[m] = ra * 32 + g0 * 4;          // holds source granule 2fkg (k lo)
    ar1[m] = ra * 32 + (g0 ^ 1) * 4;    // holds source granule 2fkg+1 (k hi)
  }
  int broff[8];
#pragma unroll
  for (int n = 0; n < 8; n++) {
    const int rb = wc * 128 + n * 16 + fr;
    broff[n] = rb * 32 + ((fkg ^ ((rb >> 1) & 3)) << 3);
  }

  f32x4 acc[4][8] = {};

  const int NT = K >> 5;
  // prologue: stage tile 0 into buffer 0
#pragma unroll
  for (int c = 0; c < 4; c++) {
    load_lds16(hidden + aoff[c], sA + ldsA[c]);
    load_lds16(BTh + boff[c], sB + ldsB[c]);
  }
  __syncthreads();

  int cur = 0;
  for (int t = 0; t < NT; t++) {
    const int boA = cur * (128 * 32);
    const int boB = cur * (256 * 32);
    const int nxA = (cur ^ 1) * (128 * 32);
    const int nxB = (cur ^ 1) * (256 * 32);
    if (t + 1 < NT) {  // issue next-tile stage BEFORE compute (overlap)
      const int k0 = (t + 1) << 5;
#pragma unroll
      for (int c = 0; c < 4; c++) {
        load_lds16(hidden + aoff[c] + k0, sA + nxA + ldsA[c]);
        load_lds16(BTh + boff[c] + k0, sB + nxB + ldsB[c]);
      }
    }
    f16x8 a[4], bh[8];
#pragma unroll
    for (int m = 0; m < 4; m++) {
      f32x4 lo = *(const f32x4*)(sA + boA + ar0[m]);
      f32x4 hi = *(const f32x4*)(sA + boA + ar1[m]);
#pragma unroll
      for (int j = 0; j < 4; j++) {
        a[m][j] = (_Float16)lo[j];
        a[m][j + 4] = (_Float16)hi[j];
      }
    }
#pragma unroll
    for (int n = 0; n < 8; n++) bh[n] = *(const f16x8*)(sB + boB + broff[n]);
    __builtin_amdgcn_s_setprio(1);
#pragma unroll
    for (int m = 0; m < 4; m++)
#pragma unroll
      for (int n = 0; n < 8; n++)
        acc[m][n] = __builtin_amdgcn_mfma_f32_16x16x32_f16(a[m], bh[n], acc[m][n], 0, 0, 0);
    __builtin_amdgcn_s_setprio(0);
    __syncthreads();
    cur ^= 1;
  }

  // epilogue: C/D layout col=lane&15, row=(lane>>4)*4+j; f16 out
#pragma unroll
  for (int m = 0; m < 4; m++) {
    const int row = bm + wr * 64 + m * 16 + fkg * 4;
#pragma unroll
    for (int n = 0; n < 8; n++) {
      const int col = bn + wc * 128 + n * 16 + fr;
      const float bsv = bias[col];
#pragma unroll
      for (int j = 0; j < 4; j++) {
        const float v = acc[m][n][j] + bsv;
        Cout[(size_t)(row + j) * Nn + col] =
            __builtin_bit_cast(unsigned short, (_Float16)v);
      }
    }
  }

  // V column-sum partials (block-uniform branch; barriers safe).
  // vred overlays sA — dead after the K-loop's final __syncthreads().
  if (bn >= 2048) {
    float* vred = (float*)sA;  // [wr][wc][n][fr] = [2][2][8][16] floats
    float csum[8];
#pragma unroll
    for (int n = 0; n < 8; n++) {
      float s = 0.f;
#pragma unroll
      for (int m = 0; m < 4; m++)
#pragma unroll
        for (int j = 0; j < 4; j++) s += acc[m][n][j];
      s += __shfl_xor(s, 16);
      s += __shfl_xor(s, 32);
      csum[n] = s;              // this wave's 64-row column sum
    }
    __syncthreads();  // all waves past sA reads (K-loop done) + TBAA order
    if (fkg == 0) {
#pragma unroll
      for (int n = 0; n < 8; n++)
        vred[(((wr * 2 + wc) * 8) + n) * 16 + fr] = csum[n];
    }
    __syncthreads();
    if (wr == 0 && fkg == 0) {
#pragma unroll
      for (int n = 0; n < 8; n++) {
        const int d = bn - 2048 + wc * 128 + n * 16 + fr;
        vpart[(size_t)(bm >> 7) * 1024 + d] =
            csum[n] + vred[(((1 * 2 + wc) * 8) + n) * 16 + fr];
      }
    }
  }
}

// ---------------------------------------------------------------------------
// pass1 (FUSED attn-row write + FUSED vsum combine): 4 heads per block.
// vsum computed inline from vpart partials + 1024*bv (same add order as the
// old vsum_comb -> bit-identical). Rows >= SROWS fuse-write their attn row.
// rowbuf fill + barriers UNCONDITIONAL (SROWS boundary wave- not
// block-uniform); barriers REQUIRED between mixed f32x4/float LDS (TBAA).
// ---------------------------------------------------------------------------
__global__ __launch_bounds__(256) void attn_pass1(
    const unsigned short* __restrict__ qkv16, const float* __restrict__ vpart,
    const float* __restrict__ biasq, const int* __restrict__ graph,
    float* __restrict__ pbuf, float* __restrict__ basebuf,
    unsigned short* __restrict__ O16, float* __restrict__ attn) {
  const int blk = blockIdx.x;         // b*4096 + hg*1024 + n
  const int n = blk & (N - 1);
  const int hg = (blk >> 10) & 3;
  const int b = blk >> 12;
  const int wave = threadIdx.x >> 6;
  const int lane = threadIdx.x & 63;
  const int h = hg * 4 + wave;
  const int bid = (b * H + h) * N + n;  // attn row id

  __shared__ float q_sh[4][DEPTH];
  __shared__ int g_sh[W];
  __shared__ float p_sh[4][W];
  __shared__ float rowbuf[4][N];      // 16 KB: per-wave attn row staging

  const unsigned short* qrow = qkv16 + (size_t)(b * N + n) * LDQKV + h * DEPTH;
  q_sh[wave][lane] = h2f(qrow[lane]);
  if (threadIdx.x < W) g_sh[threadIdx.x] = graph[n * W + threadIdx.x];
  __syncthreads();

  const int w = lane >> 1;
  const int half = lane & 1;
  const unsigned short* krow =
      qkv16 + 1024 + (size_t)(b * N + g_sh[w]) * LDQKV + h * DEPTH + half * 32;
  float acc = 0.f;
#pragma unroll
  for (int j8 = 0; j8 < 4; j8++) {
    us8 kv = *(const us8*)(krow + j8 * 8);
    const float* qh = &q_sh[wave][half * 32 + j8 * 8];
#pragma unroll
    for (int e = 0; e < 8; e++) acc += h2f(kv[e]) * qh[e];
  }
  acc += __shfl_xor(acc, 1);
  const float dot = acc * 0.125f;

  float m = dot;
#pragma unroll
  for (int off = 2; off < 64; off <<= 1) m = fmaxf(m, __shfl_xor(m, off));
  m = fmaxf(m, 0.f);

  const float e = expf(dot - m);
  float s = e;
#pragma unroll
  for (int off = 1; off < 64; off <<= 1) s += __shfl_xor(s, off);
  s *= 0.5f;

  const float em = expf(-m);
  const float Z = (float)(N - W) * em + s;
  const float inv = 1.f / Z;
  const float base = em * inv;   // wave-uniform
  const float pw = e * inv;

  if (half == 0) p_sh[wave][w] = pw;
  __syncthreads();

  const bool fused = (bid >= SROWS);  // wave-uniform
  if (!fused) {
    if (half == 0) pbuf[(size_t)bid * W + w] = pw;
    if (lane == 0) basebuf[bid] = base;
  }

  // inline vsum (same order as old vsum_comb: bias term then c=0..7)
  const int col = h * DEPTH + lane;
  float vs = 1024.0f * biasq[2048 + col];
#pragma unroll
  for (int c = 0; c < 8; c++) vs += vpart[(size_t)(b * 8 + c) * 1024 + col];

  const unsigned short* vbase = qkv16 + 2048;
  float ov = base * vs;
#pragma unroll 4
  for (int ww = 0; ww < W; ww++) {
    ov += (p_sh[wave][ww] - base) *
          h2f(vbase[(size_t)(b * N + g_sh[ww]) * LDQKV + col]);
  }
  _Float16 hh = (_Float16)ov;
  O16[(size_t)(b * N + n) * D + col] = __builtin_bit_cast(unsigned short, hh);

  // attn-row staging: fill + barriers UNCONDITIONAL; scatter/store wave-uniform
  f32x4* rw = (f32x4*)rowbuf[wave];
  f32x4 b4v = {base, base, base, base};
#pragma unroll
  for (int i = 0; i < 4; i++) rw[lane + 64 * i] = b4v;
  __syncthreads();  // order fill before scatter (mixed-type LDS, TBAA)
  if (fused && half == 0) rowbuf[wave][g_sh[w]] = pw;
  __syncthreads();  // order scatter before vector read
  if (fused) {
    f32x4* dst = (f32x4*)(attn + (size_t)bid * N);
#pragma unroll
    for (int i = 0; i < 4; i++)
      __builtin_nontemporal_store(rw[lane + 64 * i], dst + lane + 64 * i);
  }
}

// ---------------------------------------------------------------------------
// MERGED: O-projection GEMM (256 blocks) + fill of attn rows [0,6144)
// (disjoint from gemm_o's inputs O16/WoTh in rows [6144,8704)).
// ---------------------------------------------------------------------------
__global__ __launch_bounds__(256, 4) void gemm_o_fill(
    const unsigned short* __restrict__ A16, const unsigned short* __restrict__ BTh,
    const float* __restrict__ bias, float* __restrict__ Cout,
    const float* __restrict__ pbuf, const float* __restrict__ basebuf,
    const int* __restrict__ graph, float* __restrict__ attn, int K, int Nn) {
  __shared__ __align__(16) unsigned short sA[2 * 128 * 32];
  __shared__ __align__(16) unsigned short sB[2 * 128 * 32];

  const int blk = blockIdx.x;
  if (blk >= 256) {  // ---- fill section: rows [0, 6144) ----
    fill_row((float*)sA, pbuf, basebuf, graph, attn, blk - 256, threadIdx.x);
    return;
  }

  // ---- gemm_o section (proven 128x128, fp32 out, 2-phase dbuf) ----
  const int tid = threadIdx.x;
  const int lane = tid & 63;
  const int wave = tid >> 6;
  const int wr = wave >> 1, wc = wave & 1;

  int bid = blk;                       // nwg = 256, gx = 8 (8x32 tiles)
  bid = (bid & 7) * 32 + (bid >> 3);   // T1 XCD swizzle
  const int bm = (bid >> 3) * 128;
  const int bn = (bid & 7) * 128;

  size_t aoff[2], boff[2];
  int ldsoff[2];
#pragma unroll
  for (int c = 0; c < 2; c++) {
    const int chunk = wave + 4 * c;
    const int e = chunk * 512 + lane * 8;
    const int r = e >> 5;
    const int kpos = (e >> 3) & 3;
    const int ksrc = kpos ^ ((r >> 1) & 3);
    aoff[c] = (size_t)(bm + r) * K + ksrc * 8;
    boff[c] = (size_t)(bn + r) * K + ksrc * 8;
    ldsoff[c] = chunk * 512;
  }

  const int fr = lane & 15;
  const int fkg = lane >> 4;

  int aroff[4], broff[4];
#pragma unroll
  for (int m = 0; m < 4; m++) {
    const int ra = wr * 64 + m * 16 + fr;
    aroff[m] = ra * 32 + ((fkg ^ ((ra >> 1) & 3)) << 3);
    const int rb = wc * 64 + m * 16 + fr;
    broff[m] = rb * 32 + ((fkg ^ ((rb >> 1) & 3)) << 3);
  }

  f32x4 acc[4][4] = {};

  const int NT = K >> 5;
#pragma unroll
  for (int c = 0; c < 2; c++) {
    load_lds16(A16 + aoff[c], sA + ldsoff[c]);
    load_lds16(BTh + boff[c], sB + ldsoff[c]);
  }
  __syncthreads();

  int cur = 0;
  for (int t = 0; t < NT; t++) {
    const int bo_ = cur * (128 * 32);
    const int nx_ = (cur ^ 1) * (128 * 32);
    if (t + 1 < NT) {
      const int k0 = (t + 1) << 5;
#pragma unroll
      for (int c = 0; c < 2; c++) {
        load_lds16(A16 + aoff[c] + k0, sA + nx_ + ldsoff[c]);
        load_lds16(BTh + boff[c] + k0, sB + nx_ + ldsoff[c]);
      }
    }
    f16x8 a[4], bh[4];
#pragma unroll
    for (int m = 0; m < 4; m++) a[m] = *(const f16x8*)(sA + bo_ + aroff[m]);
#pragma unroll
    for (int n = 0; n < 4; n++) bh[n] = *(const f16x8*)(sB + bo_ + broff[n]);
    __builtin_amdgcn_s_setprio(1);
#pragma unroll
    for (int m = 0; m < 4; m++)
#pragma unroll
      for (int n = 0; n < 4; n++)
        acc[m][n] = __builtin_amdgcn_mfma_f32_16x16x32_f16(a[m], bh[n], acc[m][n], 0, 0, 0);
    __builtin_amdgcn_s_setprio(0);
    __syncthreads();
    cur ^= 1;
  }

#pragma unroll
  for (int m = 0; m < 4; m++) {
    const int row = bm + wr * 64 + m * 16 + fkg * 4;
#pragma unroll
    for (int n = 0; n < 4; n++) {
      const int col = bn + wc * 64 + n * 16 + fr;
      const float bsv = bias[col];
#pragma unroll
      for (int j = 0; j < 4; j++)
        Cout[(size_t)(row + j) * Nn + col] = acc[m][n][j] + bsv;
    }
  }
}

// ---------------------------------------------------------------------------
// Last fill: rows [6144, 8704) — O16/WoTh regions, consumed by gemm_o_fill.
// ---------------------------------------------------------------------------
__global__ __launch_bounds__(256) void attn_fill_last(
    const float* __restrict__ pbuf, const float* __restrict__ basebuf,
    const int* __restrict__ graph, float* __restrict__ attn) {
  __shared__ __align__(16) float rowf[N];
  fill_row(rowf, pbuf, basebuf, graph, attn, 6144 + blockIdx.x, threadIdx.x);
}

// ---------------------------------------------------------------------------
extern "C" void kernel_launch(void* const* d_in, const int* in_sizes, int n_in,
                              void* d_out, int out_size, void* d_ws, size_t ws_size,
                              hipStream_t stream) {
  const float* hidden = (const float*)d_in[0];
  const float* wq = (const float*)d_in[1];
  const float* bq = (const float*)d_in[2];
  const float* wk = (const float*)d_in[3];
  const float* bk = (const float*)d_in[4];
  const float* wv = (const float*)d_in[5];
  const float* bv = (const float*)d_in[6];
  const float* wo = (const float*)d_in[7];
  const float* bo = (const float*)d_in[8];
  const int* graph = (const int*)d_in[9];

  float* out0 = (float*)d_out;                 // (B,N,D) final output
  float* attnp = out0 + (size_t)B * N * D;     // (B,H,N,N)

  // scratch in attn rows:
  //   [0,   6M): qkv16   (live through pass1)
  //   [6M,  8M): O16     (live through gemm_o_fill)
  //   [8M, 8.5M): WoTh   (live through gemm_o_fill)
  //   [8.5M,10M): BTh    (dead after gemm_qkv -> fuse-written by pass1)
  const size_t M1 = (size_t)1024 * 1024;
  unsigned short* qkv16 = (unsigned short*)attnp;
  unsigned short* O16 = (unsigned short*)(attnp + 6 * M1);
  unsigned short* WoTh = (unsigned short*)(attnp + 8 * M1);
  unsigned short* BTh = (unsigned short*)(attnp + 8 * M1 + 524288);

  // ws layout (no overlays — pass1 reads biasq/vpart while writing pbuf):
  float* pbuf = (float*)d_ws;                        // 2M floats (8 MB)
  float* basebuf = pbuf + (size_t)B * H * N * W;     // 65536
  float* biasq = basebuf + (size_t)B * H * N;        // 3072 (pad to 4096)
  float* vpart = biasq + 4096;                       // 32768 ([32][1024])
  // total ~8.39 MB < 8.67 MB proven

  prep_all<<<1036, 256, 0, stream>>>(wq, wk, wv, wo, bq, bk, bv,
                                     BTh, WoTh, biasq);

  gemm_qkv<<<dim3(12, 32), 256, 0, stream>>>(hidden, BTh, biasq, qkv16, vpart,
                                             1024, 3072);

  attn_pass1<<<B * 4 * N, 256, 0, stream>>>(qkv16, vpart, biasq, graph, pbuf,
                                            basebuf, O16, attnp);

  // merged: O-projection (256 blocks) + fill rows [0,6144) (6144 blocks)
  gemm_o_fill<<<256 + 6144, 256, 0, stream>>>(O16, WoTh, bo, out0, pbuf,
                                              basebuf, graph, attnp,
                                              1024, 1024);

  attn_fill_last<<<8704 - 6144, 256, 0, stream>>>(pbuf, basebuf, graph, attnp);
}

// Round 20
// 137.813 us; speedup vs baseline: 1.0764x; 1.0764x over previous
//
#include <hip/hip_runtime.h>
#include <hip/hip_bf16.h>

constexpr int B = 4;
constexpr int N = 1024;
constexpr int D = 1024;
constexpr int H = 16;
constexpr int DEPTH = 64;
constexpr int W = 32;
constexpr int LDQKV = 3072;   // fused q|k|v row stride (f16 elements)

typedef _Float16 f16x8 __attribute__((ext_vector_type(8)));
typedef float f32x4 __attribute__((ext_vector_type(4)));
typedef unsigned short us8 __attribute__((ext_vector_type(8)));
typedef unsigned short us4 __attribute__((ext_vector_type(4)));

__device__ __forceinline__ float h2f(unsigned short u) {
  return (float)__builtin_bit_cast(_Float16, u);
}

// ---------------------------------------------------------------------------
// async global->LDS, 16B per lane (wave-uniform LDS base, HW adds lane*16)
// ---------------------------------------------------------------------------
__device__ __forceinline__ void load_lds16(const void* g, void* l) {
  unsigned int lo = (unsigned int)(unsigned long long)l;
  __builtin_amdgcn_global_load_lds(
      (const __attribute__((address_space(1))) unsigned int*)g,
      (__attribute__((address_space(3))) unsigned int*)lo, 16, 0, 0);
}

// ---------------------------------------------------------------------------
// attn-row fill helper: base everywhere, p at graph positions, NT store.
// Barriers between mixed f32x4/float LDS accesses are REQUIRED (TBAA).
// ---------------------------------------------------------------------------
__device__ __forceinline__ void fill_row(float* rowf, const float* pbuf,
                                         const float* basebuf,
                                         const int* graph, float* attn,
                                         int row, int t) {
  const int n = row & (N - 1);
  const float base = basebuf[row];
  f32x4* rw = (f32x4*)rowf;
  rw[t] = (f32x4){base, base, base, base};
  __syncthreads();
  if (t < W) rowf[graph[n * W + t]] = pbuf[(size_t)row * W + t];
  __syncthreads();
  __builtin_nontemporal_store(rw[t], (f32x4*)(attn + (size_t)row * N) + t);
}

// ---------------------------------------------------------------------------
// Fused prep (round-17 verified): grid sections
//   [0, 2048)       cvt_half: hidden fp32 -> A16 fp16
//   [2048, 3072)    txp_cvt:  wq/wk/wv/wo -> transposed fp16 (hi only)
//   [3072, 3084)    bias_concat
// ---------------------------------------------------------------------------
__global__ __launch_bounds__(256) void prep_all(
    const float* __restrict__ hidden, const float* __restrict__ wq,
    const float* __restrict__ wk, const float* __restrict__ wv,
    const float* __restrict__ wo, const float* __restrict__ bq,
    const float* __restrict__ bk, const float* __restrict__ bv,
    unsigned short* __restrict__ A16, unsigned short* __restrict__ BTh,
    unsigned short* __restrict__ WoTh, float* __restrict__ biasq) {
  __shared__ float sf[64][65];
  const int t = threadIdx.x;
  int blk = blockIdx.x;

  if (blk < 2048) {  // ---- cvt_half section ----
    const size_t i = ((size_t)blk * 256 + t) * 8;
    float4 a = *(const float4*)(hidden + i);
    float4 b = *(const float4*)(hidden + i + 4);
    float xs[8] = {a.x, a.y, a.z, a.w, b.x, b.y, b.z, b.w};
    us8 hv;
#pragma unroll
    for (int j = 0; j < 8; j++)
      hv[j] = __builtin_bit_cast(unsigned short, (_Float16)xs[j]);
    *(us8*)(A16 + i) = hv;
    return;
  }
  blk -= 2048;
  if (blk < 1024) {  // ---- txp_cvt sections (4 weights x 256 blocks) ----
    const int which = blk >> 8;       // 0=wq 1=wk 2=wv 3=wo
    const int sub = blk & 255;
    const float* w = which == 0 ? wq : which == 1 ? wk : which == 2 ? wv : wo;
    unsigned short* oh = which < 3 ? BTh : WoTh;
    const int rowOff = which < 3 ? which * 1024 : 0;

    const int tn = (sub & 15) * 64;   // src col block
    const int tk = (sub >> 4) * 64;   // src row block
#pragma unroll
    for (int i = 0; i < 4; i++) {
      int f = i * 256 + t;
      int r = f >> 4, c4 = (f & 15) * 4;
      float4 v = *(const float4*)(w + (size_t)(tk + r) * 1024 + tn + c4);
      sf[r][c4 + 0] = v.x; sf[r][c4 + 1] = v.y;
      sf[r][c4 + 2] = v.z; sf[r][c4 + 3] = v.w;
    }
    __syncthreads();
    const int n = t >> 2;             // out row (src col)
    const int kc = (t & 3) * 16;      // k chunk
    us8 hv[2];
#pragma unroll
    for (int half = 0; half < 2; half++) {
#pragma unroll
      for (int j = 0; j < 8; j++) {
        float x = sf[kc + half * 8 + j][n];
        hv[half][j] = __builtin_bit_cast(unsigned short, (_Float16)x);
      }
    }
    size_t dst = (size_t)(rowOff + tn + n) * 1024 + tk + kc;
    *(us8*)(oh + dst) = hv[0];
    *(us8*)(oh + dst + 8) = hv[1];
    return;
  }
  blk -= 1024;  // ---- bias_concat section (12 blocks) ----
  int i = blk * 256 + t;
  biasq[i] = i < 1024 ? bq[i] : (i < 2048 ? bk[i - 1024] : bv[i - 2048]);
}

// ---------------------------------------------------------------------------
// QKV GEMM (round-17 verified): 128x256 tile, wave = 64x128 (acc 4x8).
// BK=32, 4 waves, 2-phase dbuf (48 KB LDS), f16 out. Granule swizzle
// k'=k^((r>>1)&3) on global source + ds_read. T1 XCD swizzle; T5 setprio.
// V-column blocks (bn >= 2048) emit per-tile column-sum partials.
// ---------------------------------------------------------------------------
__global__ __launch_bounds__(256, 2) void gemm_qkv(
    const unsigned short* __restrict__ A16, const unsigned short* __restrict__ BTh,
    const float* __restrict__ bias, unsigned short* __restrict__ Cout,
    float* __restrict__ vpart, int K, int Nn) {
  __shared__ __align__(16) unsigned short sA[2 * 128 * 32];
  __shared__ __align__(16) unsigned short sB[2 * 256 * 32];
  __shared__ float vred[2][2][8][16];  // [wr][wc][n][fr], 2 KB

  const int tid = threadIdx.x;
  const int lane = tid & 63;
  const int wave = tid >> 6;
  const int wr = wave >> 1, wc = wave & 1;

  const int gx = gridDim.x;
  const int nwg = gx * gridDim.y;
  int bid = blockIdx.y * gx + blockIdx.x;
  bid = (bid & 7) * (nwg >> 3) + (bid >> 3);
  const int bm = (bid / gx) * 128;
  const int bn = (bid % gx) * 256;

  size_t aoff[2];
  int ldsA[2];
#pragma unroll
  for (int c = 0; c < 2; c++) {
    const int chunk = wave + 4 * c;
    const int e = chunk * 512 + lane * 8;
    const int r = e >> 5;
    const int kpos = (e >> 3) & 3;
    const int ksrc = kpos ^ ((r >> 1) & 3);
    aoff[c] = (size_t)(bm + r) * K + ksrc * 8;
    ldsA[c] = chunk * 512;
  }
  size_t boff[4];
  int ldsB[4];
#pragma unroll
  for (int c = 0; c < 4; c++) {
    const int chunk = wave + 4 * c;
    const int e = chunk * 512 + lane * 8;
    const int r = e >> 5;                   // 0..255
    const int kpos = (e >> 3) & 3;
    const int ksrc = kpos ^ ((r >> 1) & 3);
    boff[c] = (size_t)(bn + r) * K + ksrc * 8;
    ldsB[c] = chunk * 512;
  }

  const int fr = lane & 15;
  const int fkg = lane >> 4;

  int aroff[4], broff[8];
#pragma unroll
  for (int m = 0; m < 4; m++) {
    const int ra = wr * 64 + m * 16 + fr;
    aroff[m] = ra * 32 + ((fkg ^ ((ra >> 1) & 3)) << 3);
  }
#pragma unroll
  for (int n = 0; n < 8; n++) {
    const int rb = wc * 128 + n * 16 + fr;
    broff[n] = rb * 32 + ((fkg ^ ((rb >> 1) & 3)) << 3);
  }

  f32x4 acc[4][8] = {};

  const int NT = K >> 5;
#pragma unroll
  for (int c = 0; c < 2; c++) load_lds16(A16 + aoff[c], sA + ldsA[c]);
#pragma unroll
  for (int c = 0; c < 4; c++) load_lds16(BTh + boff[c], sB + ldsB[c]);
  __syncthreads();

  int cur = 0;
  for (int t = 0; t < NT; t++) {
    const int boA = cur * (128 * 32);
    const int boB = cur * (256 * 32);
    const int nxA = (cur ^ 1) * (128 * 32);
    const int nxB = (cur ^ 1) * (256 * 32);
    if (t + 1 < NT) {
      const int k0 = (t + 1) << 5;
#pragma unroll
      for (int c = 0; c < 2; c++) load_lds16(A16 + aoff[c] + k0, sA + nxA + ldsA[c]);
#pragma unroll
      for (int c = 0; c < 4; c++) load_lds16(BTh + boff[c] + k0, sB + nxB + ldsB[c]);
    }
    f16x8 a[4], bh[8];
#pragma unroll
    for (int m = 0; m < 4; m++) a[m] = *(const f16x8*)(sA + boA + aroff[m]);
#pragma unroll
    for (int n = 0; n < 8; n++) bh[n] = *(const f16x8*)(sB + boB + broff[n]);
    __builtin_amdgcn_s_setprio(1);
#pragma unroll
    for (int m = 0; m < 4; m++)
#pragma unroll
      for (int n = 0; n < 8; n++)
        acc[m][n] = __builtin_amdgcn_mfma_f32_16x16x32_f16(a[m], bh[n], acc[m][n], 0, 0, 0);
    __builtin_amdgcn_s_setprio(0);
    __syncthreads();
    cur ^= 1;
  }

  // epilogue: C/D layout col=lane&15, row=(lane>>4)*4+j; f16 out
#pragma unroll
  for (int m = 0; m < 4; m++) {
    const int row = bm + wr * 64 + m * 16 + fkg * 4;
#pragma unroll
    for (int n = 0; n < 8; n++) {
      const int col = bn + wc * 128 + n * 16 + fr;
      const float bsv = bias[col];
#pragma unroll
      for (int j = 0; j < 4; j++) {
        const float v = acc[m][n][j] + bsv;
        Cout[(size_t)(row + j) * Nn + col] =
            __builtin_bit_cast(unsigned short, (_Float16)v);
      }
    }
  }

  // V column-sum partials (block-uniform branch; barrier inside is safe)
  if (bn >= 2048) {
    float csum[8];
#pragma unroll
    for (int n = 0; n < 8; n++) {
      float s = 0.f;
#pragma unroll
      for (int m = 0; m < 4; m++)
#pragma unroll
        for (int j = 0; j < 4; j++) s += acc[m][n][j];
      s += __shfl_xor(s, 16);
      s += __shfl_xor(s, 32);
      csum[n] = s;
    }
    if (fkg == 0) {
#pragma unroll
      for (int n = 0; n < 8; n++) vred[wr][wc][n][fr] = csum[n];
    }
    __syncthreads();
    if (wr == 0 && fkg == 0) {
#pragma unroll
      for (int n = 0; n < 8; n++) {
        const int d = bn - 2048 + wc * 128 + n * 16 + fr;
        vpart[(size_t)(bm >> 7) * 1024 + d] = csum[n] + vred[1][wc][n][fr];
      }
    }
  }
}

// ---------------------------------------------------------------------------
// pass1 (FUSED attn-row write + FUSED vsum combine): 4 heads per block.
// vsum computed inline from vpart partials + 1024*bv. Rows >= srows (runtime,
// per-wave-uniform) fuse-write their attn row. rowbuf fill + barriers
// UNCONDITIONAL; barriers REQUIRED between mixed f32x4/float LDS (TBAA).
// ---------------------------------------------------------------------------
__global__ __launch_bounds__(256) void attn_pass1(
    const unsigned short* __restrict__ qkv16, const float* __restrict__ vpart,
    const float* __restrict__ biasq, const int* __restrict__ graph,
    float* __restrict__ pbuf, float* __restrict__ basebuf,
    unsigned short* __restrict__ O16, float* __restrict__ attn, int srows) {
  const int blk = blockIdx.x;         // b*4096 + hg*1024 + n
  const int n = blk & (N - 1);
  const int hg = (blk >> 10) & 3;
  const int b = blk >> 12;
  const int wave = threadIdx.x >> 6;
  const int lane = threadIdx.x & 63;
  const int h = hg * 4 + wave;
  const int bid = (b * H + h) * N + n;  // attn row id

  __shared__ float q_sh[4][DEPTH];
  __shared__ int g_sh[W];
  __shared__ float p_sh[4][W];
  __shared__ float rowbuf[4][N];      // 16 KB: per-wave attn row staging

  const unsigned short* qrow = qkv16 + (size_t)(b * N + n) * LDQKV + h * DEPTH;
  q_sh[wave][lane] = h2f(qrow[lane]);
  if (threadIdx.x < W) g_sh[threadIdx.x] = graph[n * W + threadIdx.x];
  __syncthreads();

  const int w = lane >> 1;
  const int half = lane & 1;
  const unsigned short* krow =
      qkv16 + 1024 + (size_t)(b * N + g_sh[w]) * LDQKV + h * DEPTH + half * 32;
  float acc = 0.f;
#pragma unroll
  for (int j8 = 0; j8 < 4; j8++) {
    us8 kv = *(const us8*)(krow + j8 * 8);
    const float* qh = &q_sh[wave][half * 32 + j8 * 8];
#pragma unroll
    for (int e = 0; e < 8; e++) acc += h2f(kv[e]) * qh[e];
  }
  acc += __shfl_xor(acc, 1);
  const float dot = acc * 0.125f;

  float m = dot;
#pragma unroll
  for (int off = 2; off < 64; off <<= 1) m = fmaxf(m, __shfl_xor(m, off));
  m = fmaxf(m, 0.f);

  const float e = expf(dot - m);
  float s = e;
#pragma unroll
  for (int off = 1; off < 64; off <<= 1) s += __shfl_xor(s, off);
  s *= 0.5f;

  const float em = expf(-m);
  const float Z = (float)(N - W) * em + s;
  const float inv = 1.f / Z;
  const float base = em * inv;   // wave-uniform
  const float pw = e * inv;

  if (half == 0) p_sh[wave][w] = pw;
  __syncthreads();

  const bool fused = (bid >= srows);  // wave-uniform
  if (!fused) {
    if (half == 0) pbuf[(size_t)bid * W + w] = pw;
    if (lane == 0) basebuf[bid] = base;
  }

  // inline vsum (same order as old vsum_comb: bias term then c=0..7)
  const int col = h * DEPTH + lane;
  float vs = 1024.0f * biasq[2048 + col];
#pragma unroll
  for (int c = 0; c < 8; c++) vs += vpart[(size_t)(b * 8 + c) * 1024 + col];

  const unsigned short* vbase = qkv16 + 2048;
  float ov = base * vs;
#pragma unroll 4
  for (int ww = 0; ww < W; ww++) {
    ov += (p_sh[wave][ww] - base) *
          h2f(vbase[(size_t)(b * N + g_sh[ww]) * LDQKV + col]);
  }
  _Float16 hh = (_Float16)ov;
  O16[(size_t)(b * N + n) * D + col] = __builtin_bit_cast(unsigned short, hh);

  // attn-row staging: fill + barriers UNCONDITIONAL; scatter/store wave-uniform
  f32x4* rw = (f32x4*)rowbuf[wave];
  f32x4 b4v = {base, base, base, base};
#pragma unroll
  for (int i = 0; i < 4; i++) rw[lane + 64 * i] = b4v;
  __syncthreads();  // order fill before scatter (mixed-type LDS, TBAA)
  if (fused && half == 0) rowbuf[wave][g_sh[w]] = pw;
  __syncthreads();  // order scatter before vector read
  if (fused) {
    f32x4* dst = (f32x4*)(attn + (size_t)bid * N);
#pragma unroll
    for (int i = 0; i < 4; i++)
      __builtin_nontemporal_store(rw[lane + 64 * i], dst + lane + 64 * i);
  }
}

// ---------------------------------------------------------------------------
// MERGED: O-projection GEMM (256 blocks) + fill of attn rows [0,6144)
// (disjoint from gemm_o's inputs O16/WoTh, which live in rows >= 6144 or ws).
// ---------------------------------------------------------------------------
__global__ __launch_bounds__(256, 4) void gemm_o_fill(
    const unsigned short* __restrict__ A16, const unsigned short* __restrict__ BTh,
    const float* __restrict__ bias, float* __restrict__ Cout,
    const float* __restrict__ pbuf, const float* __restrict__ basebuf,
    const int* __restrict__ graph, float* __restrict__ attn, int K, int Nn) {
  __shared__ __align__(16) unsigned short sA[2 * 128 * 32];
  __shared__ __align__(16) unsigned short sB[2 * 128 * 32];

  const int blk = blockIdx.x;
  if (blk >= 256) {  // ---- fill section: rows [0, 6144) ----
    fill_row((float*)sA, pbuf, basebuf, graph, attn, blk - 256, threadIdx.x);
    return;
  }

  // ---- gemm_o section (proven 128x128, fp32 out, 2-phase dbuf) ----
  const int tid = threadIdx.x;
  const int lane = tid & 63;
  const int wave = tid >> 6;
  const int wr = wave >> 1, wc = wave & 1;

  int bid = blk;                       // nwg = 256, gx = 8 (8x32 tiles)
  bid = (bid & 7) * 32 + (bid >> 3);   // T1 XCD swizzle
  const int bm = (bid >> 3) * 128;
  const int bn = (bid & 7) * 128;

  size_t aoff[2], boff[2];
  int ldsoff[2];
#pragma unroll
  for (int c = 0; c < 2; c++) {
    const int chunk = wave + 4 * c;
    const int e = chunk * 512 + lane * 8;
    const int r = e >> 5;
    const int kpos = (e >> 3) & 3;
    const int ksrc = kpos ^ ((r >> 1) & 3);
    aoff[c] = (size_t)(bm + r) * K + ksrc * 8;
    boff[c] = (size_t)(bn + r) * K + ksrc * 8;
    ldsoff[c] = chunk * 512;
  }

  const int fr = lane & 15;
  const int fkg = lane >> 4;

  int aroff[4], broff[4];
#pragma unroll
  for (int m = 0; m < 4; m++) {
    const int ra = wr * 64 + m * 16 + fr;
    aroff[m] = ra * 32 + ((fkg ^ ((ra >> 1) & 3)) << 3);
    const int rb = wc * 64 + m * 16 + fr;
    broff[m] = rb * 32 + ((fkg ^ ((rb >> 1) & 3)) << 3);
  }

  f32x4 acc[4][4] = {};

  const int NT = K >> 5;
#pragma unroll
  for (int c = 0; c < 2; c++) {
    load_lds16(A16 + aoff[c], sA + ldsoff[c]);
    load_lds16(BTh + boff[c], sB + ldsoff[c]);
  }
  __syncthreads();

  int cur = 0;
  for (int t = 0; t < NT; t++) {
    const int bo_ = cur * (128 * 32);
    const int nx_ = (cur ^ 1) * (128 * 32);
    if (t + 1 < NT) {
      const int k0 = (t + 1) << 5;
#pragma unroll
      for (int c = 0; c < 2; c++) {
        load_lds16(A16 + aoff[c] + k0, sA + nx_ + ldsoff[c]);
        load_lds16(BTh + boff[c] + k0, sB + nx_ + ldsoff[c]);
      }
    }
    f16x8 a[4], bh[4];
#pragma unroll
    for (int m = 0; m < 4; m++) a[m] = *(const f16x8*)(sA + bo_ + aroff[m]);
#pragma unroll
    for (int n = 0; n < 4; n++) bh[n] = *(const f16x8*)(sB + bo_ + broff[n]);
    __builtin_amdgcn_s_setprio(1);
#pragma unroll
    for (int m = 0; m < 4; m++)
#pragma unroll
      for (int n = 0; n < 4; n++)
        acc[m][n] = __builtin_amdgcn_mfma_f32_16x16x32_f16(a[m], bh[n], acc[m][n], 0, 0, 0);
    __builtin_amdgcn_s_setprio(0);
    __syncthreads();
    cur ^= 1;
  }

#pragma unroll
  for (int m = 0; m < 4; m++) {
    const int row = bm + wr * 64 + m * 16 + fkg * 4;
#pragma unroll
    for (int n = 0; n < 4; n++) {
      const int col = bn + wc * 64 + n * 16 + fr;
      const float bsv = bias[col];
#pragma unroll
      for (int j = 0; j < 4; j++)
        Cout[(size_t)(row + j) * Nn + col] = acc[m][n][j] + bsv;
    }
  }
}

// ---------------------------------------------------------------------------
// Last fill: rows [6144, srows) — only needed when scratch extends past 6144
// (small-ws fallback). Runs after gemm_o_fill has consumed O16/WoTh.
// ---------------------------------------------------------------------------
__global__ __launch_bounds__(256) void attn_fill_last(
    const float* __restrict__ pbuf, const float* __restrict__ basebuf,
    const int* __restrict__ graph, float* __restrict__ attn) {
  __shared__ __align__(16) float rowf[N];
  fill_row(rowf, pbuf, basebuf, graph, attn, 6144 + blockIdx.x, threadIdx.x);
}

// ---------------------------------------------------------------------------
extern "C" void kernel_launch(void* const* d_in, const int* in_sizes, int n_in,
                              void* d_out, int out_size, void* d_ws, size_t ws_size,
                              hipStream_t stream) {
  const float* hidden = (const float*)d_in[0];
  const float* wq = (const float*)d_in[1];
  const float* bq = (const float*)d_in[2];
  const float* wk = (const float*)d_in[3];
  const float* bk = (const float*)d_in[4];
  const float* wv = (const float*)d_in[5];
  const float* bv = (const float*)d_in[6];
  const float* wo = (const float*)d_in[7];
  const float* bo = (const float*)d_in[8];
  const int* graph = (const int*)d_in[9];

  float* out0 = (float*)d_out;                 // (B,N,D) final output
  float* attnp = out0 + (size_t)B * N * D;     // (B,H,N,N)

  const size_t M1 = (size_t)1024 * 1024;

  // common ws: pbuf | basebuf | biasq | vpart  (~8.39 MB, proven budget)
  float* pbuf = (float*)d_ws;                        // 2M floats
  float* basebuf = pbuf + (size_t)B * H * N * W;     // 65536
  float* biasq = basebuf + (size_t)B * H * N;        // 3072 (pad to 4096)
  float* vpart = biasq + 4096;                       // 32768 ([32][1024])
  float* ws_end = vpart + 32768;                     // 4,820,992 bytes*4 so far

  // qkv16 always in attn rows [0, 6M); A16 in [6M, 8M) (dead after gemm_qkv)
  unsigned short* qkv16 = (unsigned short*)attnp;
  unsigned short* A16 = (unsigned short*)(attnp + 6 * M1);

  // ws-size branch: O16 (4M ush) + WoTh (1M ush) in ws if it fits
  const size_t need = ((size_t)ws_end - (size_t)d_ws) +
                      (4 * M1 + 1 * M1) * sizeof(unsigned short);
  const bool bigws = ws_size >= need;

  unsigned short *O16, *WoTh, *BTh;
  int srows;
  if (bigws) {
    O16 = (unsigned short*)ws_end;                   // 4M ush in ws
    WoTh = O16 + 4 * M1;                             // 1M ush in ws
    BTh = (unsigned short*)(attnp + 8 * M1);         // [8M, 9.5M) attn rows
    srows = 6144;   // only qkv16 live during pass1
  } else {
    O16 = A16;                                       // overlay [6M, 8M)
    WoTh = (unsigned short*)(attnp + 8 * M1);        // [8M, 8.5M)
    BTh = (unsigned short*)(attnp + 8 * M1 + 524288); // [8.5M, 10M)
    srows = 8704;   // qkv16 | O16 | WoTh live during pass1
  }

  prep_all<<<3084, 256, 0, stream>>>(hidden, wq, wk, wv, wo, bq, bk, bv,
                                     A16, BTh, WoTh, biasq);

  gemm_qkv<<<dim3(12, 32), 256, 0, stream>>>(A16, BTh, biasq, qkv16, vpart,
                                             1024, 3072);

  attn_pass1<<<B * 4 * N, 256, 0, stream>>>(qkv16, vpart, biasq, graph, pbuf,
                                            basebuf, O16, attnp, srows);

  // merged: O-projection (256 blocks) + fill rows [0,6144) (6144 blocks)
  gemm_o_fill<<<256 + 6144, 256, 0, stream>>>(O16, WoTh, bo, out0, pbuf,
                                              basebuf, graph, attnp,
                                              1024, 1024);

  if (srows > 6144)
    attn_fill_last<<<srows - 6144, 256, 0, stream>>>(pbuf, basebuf, graph,
                                                     attnp);
}